// Round 10
// baseline (1680.230 us; speedup 1.0000x reference)
//
#include <hip/hip_runtime.h>
#include <hip/hip_fp16.h>

typedef _Float16 half_t;
typedef __attribute__((ext_vector_type(8))) _Float16 half8;
typedef __attribute__((ext_vector_type(4))) float f32x4;

#define AS1 __attribute__((address_space(1)))
#define AS3 __attribute__((address_space(3)))

__device__ __forceinline__ void gload16(const half_t* g, half_t* l) {
  __builtin_amdgcn_global_load_lds((const AS1 void*)g, (AS3 void*)l, 16, 0, 0);
}

// ---------------- B-spline basis, UNIFORM grid (h=0.4, knots (j-3)*0.4-1).
__device__ __forceinline__ void bspline8u(float x, float out[8]) {
  float g[12];
#pragma unroll
  for (int j = 0; j < 12; ++j) g[j] = (float)(j - 3) * 0.4f - 1.0f;
  float b[11];
#pragma unroll
  for (int j = 0; j < 11; ++j)
    b[j] = (x >= g[j] && x < g[j + 1]) ? 1.0f : 0.0f;
#pragma unroll
  for (int k = 1; k <= 3; ++k) {
#pragma unroll
    for (int j = 0; j + k < 11; ++j) {
      float rl = 1.0f / (g[j + k] - g[j]);         // constant-folded
      float rr = 1.0f / (g[j + k + 1] - g[j + 1]); // constant-folded
      b[j] = ((x - g[j]) * rl) * b[j] + ((g[j + k + 1] - x) * rr) * b[j + 1];
    }
  }
#pragma unroll
  for (int j = 0; j < 8; ++j) out[j] = b[j];
}

// ---------------- weight conversion: fp32 (base,spline*scaler) -> fp16
__global__ void wconv_kernel(const float* __restrict__ bw, const float* __restrict__ sw,
                             const float* __restrict__ sc, half_t* __restrict__ W,
                             int ibits, int ldw) {
  int idx = blockIdx.x * 256 + threadIdx.x;
  int o = idx >> ibits;
  int i = idx & ((1 << ibits) - 1);
  int c = i >> 10;
  int il = i & 1023;
  float b = bw[idx];
  float scv = sc[idx];
  const float4* svp = (const float4*)sw;
  float4 s0 = svp[(size_t)idx * 2];
  float4 s1 = svp[(size_t)idx * 2 + 1];
  half_t* wrow = W + (size_t)o * ldw + c * 9216;
  wrow[il] = (half_t)b;
  half8 hv;
  hv[0] = (half_t)(s0.x * scv); hv[1] = (half_t)(s0.y * scv);
  hv[2] = (half_t)(s0.z * scv); hv[3] = (half_t)(s0.w * scv);
  hv[4] = (half_t)(s1.x * scv); hv[5] = (half_t)(s1.y * scv);
  hv[6] = (half_t)(s1.z * scv); hv[7] = (half_t)(s1.w * scv);
  *(half8*)&wrow[1024 + il * 8] = hv;
}

// ---------------- activation expansion: v -> [silu(v) | basis(v)[8]] fp16
// Optionally also copies v to xout (fuses the out=x residual baseline).
template <typename ST>
__global__ void expand_kernel(const ST* __restrict__ src, half_t* __restrict__ dst,
                              int Isrc, int i0, int dsub, int kexp,
                              float* __restrict__ xout) {
  int idx = blockIdx.x * 256 + threadIdx.x;
  int n = idx >> 10;
  int il = idx & 1023;
  float v = (float)src[(size_t)n * Isrc + i0 + il];
  float bs[8];
  bspline8u(v, bs);
  half_t* drow = dst + (size_t)n * kexp + (size_t)dsub * 9216;
  drow[il] = (half_t)(v / (1.0f + expf(-v)));
  half8 hb;
#pragma unroll
  for (int k = 0; k < 8; ++k) hb[k] = (half_t)bs[k];
  *(half8*)&drow[1024 + il * 8] = hb;
  if (xout) xout[(size_t)n * Isrc + il] = v;
}

// Single-pass expansion of all 4 layer-2 chunks (reads Hh once).
__global__ void expand4_kernel(const half_t* __restrict__ src, half_t* __restrict__ dst,
                               int ldk2) {
  int idx = blockIdx.x * 256 + threadIdx.x;      // over 4096*4096
  int n = idx >> 12;
  int il4 = idx & 4095;
  int c = il4 >> 10;
  int il = il4 & 1023;
  float v = (float)src[(size_t)n * 4096 + il4];
  float bs[8];
  bspline8u(v, bs);
  half_t* drow = dst + (size_t)n * ldk2 + (size_t)c * 9216;
  drow[il] = (half_t)(v / (1.0f + expf(-v)));
  half8 hb;
#pragma unroll
  for (int k = 0; k < 8; ++k) hb[k] = (half_t)bs[k];
  *(half8*)&drow[1024 + il * 8] = hb;
}

// ---------------- 8-phase 256x256 GEMM, READ-AHEAD edition.
// Every phase's MFMA consumes fragments ds_read in the PREVIOUS phase, so
// LDS-read latency hides under the barrier + other waves' MFMA (the m201
// pattern we were missing; round-9 analysis: phase floor ~600cyc, ours 1341
// with same-phase reads). Per-phase vmcnt(6) pacing (best of 3 tested
// disciplines). Frag buffers: afX/afY (af0/af1 families, both live at
// crossover), bAX/bAY, bBv single. +48 VGPR vs round-6 — free: LDS caps at
// 1 block/CU (8 waves) and 2 waves/SIMD fit the unified file at ~320 regs;
// launch_bounds (512,1) so the allocator isn't capped at 256.
// Ledger (publication rule: staged p -> wave-drained p+3's vm6 -> barrier ->
// readable p+4; every read below is exactly at/after publication):
//  p1 rd bB c0h1 (stg prev-p5) | p2 rd af1c0 (prev-p6) | p3 rd af0c1
//  (prev-p7) | p4 rd bAc1 (prev-p8) | p5 rd bBc1 (p1) | p6 rd af1c1 (p2) |
//  p7 rd af0' (p3) | p8 rd bA' (p4).
// WAR: every stage >=4 phases after its region's last ds_read.
#define STA(c, t, h)                                                          \
  {                                                                           \
    int r0_ = wid * 8 + (h) * 64;                                             \
    const half_t* g_ = Abase + (size_t)(r0_ + srow) * ldkA +                  \
                       (size_t)(t) * 64 + scol;                               \
    gload16(g_, &As[c][r0_ * 64]);                                            \
    gload16(g_ + (size_t)128 * ldkA, &As[c][(r0_ + 128) * 64]);               \
  }
#define STB(c, t, h)                                                          \
  {                                                                           \
    int r0_ = (wid >> 2) * 64 + (wid & 3) * 8 + (h) * 32;                     \
    const half_t* g_ = Bbase + (size_t)(r0_ + srow) * ldkB +                  \
                       (size_t)(t) * 64 + scol;                               \
    gload16(g_, &Bs[c][r0_ * 64]);                                            \
    gload16(g_ + (size_t)128 * ldkB, &Bs[c][(r0_ + 128) * 64]);               \
  }
#define LOADAF(dst, c, mh)                                                    \
  _Pragma("unroll") for (int a = 0; a < 4; ++a) {                             \
    int row_ = wm * 128 + (mh) * 64 + a * 16 + (lane & 15);                   \
    _Pragma("unroll") for (int ks = 0; ks < 2; ++ks) {                        \
      int ch_ = (ks * 4 + (lane >> 4)) ^ (lane & 7);                          \
      dst[a][ks] = *(const half8*)&As[c][row_ * 64 + ch_ * 8];                \
    }                                                                         \
  }
#define LOADBF(dst, c, nh)                                                    \
  _Pragma("unroll") for (int b = 0; b < 2; ++b) {                             \
    int row_ = wn * 64 + (nh) * 32 + b * 16 + (lane & 15);                    \
    _Pragma("unroll") for (int ks = 0; ks < 2; ++ks) {                        \
      int ch_ = (ks * 4 + (lane >> 4)) ^ (lane & 7);                          \
      dst[b][ks] = *(const half8*)&Bs[c][row_ * 64 + ch_ * 8];                \
    }                                                                         \
  }
#define VM6 asm volatile("s_waitcnt vmcnt(6)" ::: "memory");
#define VM4 asm volatile("s_waitcnt vmcnt(4)" ::: "memory");
#define VM2 asm volatile("s_waitcnt vmcnt(2)" ::: "memory");
#define VM0 asm volatile("s_waitcnt vmcnt(0)" ::: "memory");
#define NOVM
#define DOPHASE(afv, bfv, mh, nh, LOADS, STAGE, WAIT)                         \
  do {                                                                        \
    LOADS                                                                     \
    STAGE                                                                     \
    WAIT                                                                      \
    __builtin_amdgcn_s_barrier();                                             \
    __builtin_amdgcn_sched_barrier(0);                                        \
    __builtin_amdgcn_s_setprio(1);                                            \
    _Pragma("unroll") for (int ks = 0; ks < 2; ++ks)                          \
      _Pragma("unroll") for (int a = 0; a < 4; ++a)                           \
        _Pragma("unroll") for (int b = 0; b < 2; ++b)                         \
          acc[(mh) * 4 + a][(nh) * 2 + b] =                                   \
              __builtin_amdgcn_mfma_f32_16x16x32_f16(                         \
                  afv[a][ks], bfv[b][ks], acc[(mh) * 4 + a][(nh) * 2 + b],    \
                  0, 0, 0);                                                   \
    __builtin_amdgcn_s_setprio(0);                                            \
    __builtin_amdgcn_s_barrier();                                             \
    __builtin_amdgcn_sched_barrier(0);                                        \
  } while (0)

template <int MODE>
__global__ __launch_bounds__(512, 1) void gemm8_kernel(
    const half_t* __restrict__ A, const half_t* __restrict__ B,
    int ldkA, int ldkB, int kzLen,
    float* __restrict__ Cout, half_t* __restrict__ Hout, int ldc) {
  __shared__ __align__(16) half_t As[2][256 * 64];
  __shared__ __align__(16) half_t Bs[2][256 * 64];

  const int tid = threadIdx.x;
  const int wid = tid >> 6;
  const int lane = tid & 63;
  const int wm = wid >> 2;
  const int wn = wid & 3;

  const half_t* Abase = A + (size_t)blockIdx.x * 256 * ldkA +
                        (size_t)blockIdx.z * kzLen;
  const half_t* Bbase = B + (size_t)blockIdx.y * 256 * ldkB +
                        (size_t)blockIdx.z * kzLen;

  const int srow = lane >> 3;                    // row within 8-row region
  const int scol = ((lane & 7) ^ srow) * 8;      // pre-swizzled 16B chunk

  const int nt = kzLen >> 6;                     // K-tiles (BK=64), even, >=4

  f32x4 acc[8][4] = {};
  half8 afX[4][2], afY[4][2], bAX[2][2], bAY[2][2], bBv[2][2];

  // Prologue: tile0 complete + tile1 {A-h0, B-h0}; drain; barrier; then
  // read-ahead p1's fragments (af0c0, bA c0).
  STA(0, 0, 0); STB(0, 0, 0); STB(0, 0, 1); STA(0, 0, 1);
  STA(1, 1, 0); STB(1, 1, 0);
  asm volatile("s_waitcnt vmcnt(0)" ::: "memory");
  __builtin_amdgcn_s_barrier();
  __builtin_amdgcn_sched_barrier(0);
  LOADAF(afX, 0, 0)
  LOADBF(bAX, 0, 0)

  for (int i = 0; i < (nt >> 1) - 1; ++i) {
    const int t = 2 * i;
    DOPHASE(afX, bAX, 0, 0, { LOADBF(bBv, 0, 1) }, { STB(1, t + 1, 1); }, VM6);
    DOPHASE(afX, bBv, 0, 1, { LOADAF(afY, 0, 1) }, { STA(1, t + 1, 1); }, VM6);
    DOPHASE(afY, bBv, 1, 1, { LOADAF(afX, 1, 0) }, { STA(0, t + 2, 0); }, VM6);
    DOPHASE(afY, bAX, 1, 0, { LOADBF(bAY, 1, 0) }, { STB(0, t + 2, 0); }, VM6);
    DOPHASE(afX, bAY, 0, 0, { LOADBF(bBv, 1, 1) }, { STB(0, t + 2, 1); }, VM6);
    DOPHASE(afX, bBv, 0, 1, { LOADAF(afY, 1, 1) }, { STA(0, t + 2, 1); }, VM6);
    DOPHASE(afY, bBv, 1, 1, { LOADAF(afX, 0, 0) }, { STA(1, t + 3, 0); }, VM6);
    DOPHASE(afY, bAY, 1, 0, { LOADBF(bAX, 0, 0) }, { STB(1, t + 3, 0); }, VM6);
  }
  {
    const int t = nt - 2;  // peeled tail: stage only t+1's remaining halves
    DOPHASE(afX, bAX, 0, 0, { LOADBF(bBv, 0, 1) }, { STB(1, t + 1, 1); }, VM6);
    DOPHASE(afX, bBv, 0, 1, { LOADAF(afY, 0, 1) }, { STA(1, t + 1, 1); }, VM6);
    DOPHASE(afY, bBv, 1, 1, { LOADAF(afX, 1, 0) }, {},                   VM4);
    DOPHASE(afY, bAX, 1, 0, { LOADBF(bAY, 1, 0) }, {},                   VM2);
    DOPHASE(afX, bAY, 0, 0, { LOADBF(bBv, 1, 1) }, {},                   VM0);
    DOPHASE(afX, bBv, 0, 1, { LOADAF(afY, 1, 1) }, {},                   NOVM);
    DOPHASE(afY, bBv, 1, 1, {},                    {},                   NOVM);
    DOPHASE(afY, bAY, 1, 0, {},                    {},                   NOVM);
  }

  const int r_lo = (lane >> 4) << 2;
  const int col0 = (int)blockIdx.y * 256 + wn * 64 + (lane & 15);
  const int row00 = (int)blockIdx.x * 256 + wm * 128 + r_lo;
#pragma unroll
  for (int mf = 0; mf < 8; ++mf)
#pragma unroll
    for (int nf = 0; nf < 4; ++nf)
#pragma unroll
      for (int j = 0; j < 4; ++j) {
        float v = acc[mf][nf][j];
        size_t off = (size_t)(row00 + mf * 16 + j) * ldc + col0 + nf * 16;
        if constexpr (MODE == 0) {
          v = 0.5f * v * (1.0f + erff(v * 0.70710678118654752f));
          Hout[off] = (half_t)v;
        } else {
          atomicAdd(&Cout[off], v);
        }
      }
}

extern "C" void kernel_launch(void* const* d_in, const int* in_sizes, int n_in,
                              void* d_out, int out_size, void* d_ws, size_t ws_size,
                              hipStream_t stream) {
  const float* x   = (const float*)d_in[0];
  const float* bw1 = (const float*)d_in[1];
  const float* sw1 = (const float*)d_in[2];
  const float* sc1 = (const float*)d_in[3];
  const float* bw2 = (const float*)d_in[4];
  const float* sw2 = (const float*)d_in[5];
  const float* sc2 = (const float*)d_in[6];
  float* out = (float*)d_out;

  const int LDK1 = 9216 + 64;
  const int LDK2 = 36864 + 64;
  const int LDK2H = 18432 + 64;

  half_t* Wbuf = (half_t*)d_ws;
  const size_t W_HALVES  = (size_t)4096 * LDK1;
  const size_t AF_HALVES = (size_t)4096 * LDK2;
  const size_t A2_HALVES = (size_t)4096 * LDK2H;
  const size_t A1_HALVES = (size_t)4096 * LDK1;
  const size_t HH_HALVES = (size_t)4096 * 4096;
  int abuf_chunks = 1;
  if (ws_size >= (W_HALVES + AF_HALVES + HH_HALVES) * sizeof(half_t))
    abuf_chunks = 4;
  else if (ws_size >= (W_HALVES + A2_HALVES + HH_HALVES) * sizeof(half_t))
    abuf_chunks = 2;
  half_t* Abuf = Wbuf + W_HALVES;
  half_t* Hh   = Abuf + (abuf_chunks == 4 ? AF_HALVES
                         : abuf_chunks == 2 ? A2_HALVES : A1_HALVES);

  const int T = 256;
  const int NB = (4096 * 1024) / T;

  // ---- layer 1 (expand1 also writes out = x, the residual baseline) ----
  wconv_kernel<<<NB, T, 0, stream>>>(bw1, sw1, sc1, Wbuf, 10, LDK1);
  expand_kernel<float><<<NB, T, 0, stream>>>(x, Abuf, 1024, 0, 0, LDK1, out);
  gemm8_kernel<0><<<dim3(16, 16, 1), 512, 0, stream>>>(
      Abuf, Wbuf, LDK1, LDK1, 9216, nullptr, Hh, 4096);

  // ---- layer 2: W2 rows [o][LDK2], data K-contiguous in [0,36864) ----
  wconv_kernel<<<NB, T, 0, stream>>>(bw2, sw2, sc2, Wbuf, 12, LDK2);
  if (abuf_chunks == 4) {
    expand4_kernel<<<4 * NB, T, 0, stream>>>(Hh, Abuf, LDK2);
    gemm8_kernel<4><<<dim3(16, 4, 4), 512, 0, stream>>>(
        Abuf, Wbuf, LDK2, LDK2, 9216, out, nullptr, 1024);
  } else if (abuf_chunks == 2) {
    for (int c = 0; c < 2; ++c) {
      expand_kernel<half_t><<<NB, T, 0, stream>>>(Hh, Abuf, 4096, c * 2048, 0, LDK2H, nullptr);
      expand_kernel<half_t><<<NB, T, 0, stream>>>(Hh, Abuf, 4096, c * 2048 + 1024, 1, LDK2H, nullptr);
      gemm8_kernel<4><<<dim3(16, 4, 4), 512, 0, stream>>>(
          Abuf, Wbuf + (size_t)c * 18432, LDK2H, LDK2, 4608, out, nullptr, 1024);
    }
  } else {
    for (int c = 0; c < 4; ++c) {
      expand_kernel<half_t><<<NB, T, 0, stream>>>(Hh, Abuf, 4096, c * 1024, 0, LDK1, nullptr);
      gemm8_kernel<4><<<dim3(16, 4, 4), 512, 0, stream>>>(
          Abuf, Wbuf + (size_t)c * 9216, LDK1, LDK2, 2304, out, nullptr, 1024);
    }
  }
}

// Round 11
// 880.525 us; speedup vs baseline: 1.9082x; 1.9082x over previous
//
#include <hip/hip_runtime.h>
#include <hip/hip_fp16.h>

typedef _Float16 half_t;
typedef __attribute__((ext_vector_type(8))) _Float16 half8;
typedef __attribute__((ext_vector_type(4))) float f32x4;

#define AS1 __attribute__((address_space(1)))
#define AS3 __attribute__((address_space(3)))

__device__ __forceinline__ void gload16(const half_t* g, half_t* l) {
  __builtin_amdgcn_global_load_lds((const AS1 void*)g, (AS3 void*)l, 16, 0, 0);
}

// ---------------- B-spline basis, UNIFORM grid (h=0.4, knots (j-3)*0.4-1).
__device__ __forceinline__ void bspline8u(float x, float out[8]) {
  float g[12];
#pragma unroll
  for (int j = 0; j < 12; ++j) g[j] = (float)(j - 3) * 0.4f - 1.0f;
  float b[11];
#pragma unroll
  for (int j = 0; j < 11; ++j)
    b[j] = (x >= g[j] && x < g[j + 1]) ? 1.0f : 0.0f;
#pragma unroll
  for (int k = 1; k <= 3; ++k) {
#pragma unroll
    for (int j = 0; j + k < 11; ++j) {
      float rl = 1.0f / (g[j + k] - g[j]);         // constant-folded
      float rr = 1.0f / (g[j + k + 1] - g[j + 1]); // constant-folded
      b[j] = ((x - g[j]) * rl) * b[j] + ((g[j + k + 1] - x) * rr) * b[j + 1];
    }
  }
#pragma unroll
  for (int j = 0; j < 8; ++j) out[j] = b[j];
}

// ---------------- weight conversion: fp32 (base,spline*scaler) -> fp16
__global__ void wconv_kernel(const float* __restrict__ bw, const float* __restrict__ sw,
                             const float* __restrict__ sc, half_t* __restrict__ W,
                             int ibits, int ldw) {
  int idx = blockIdx.x * 256 + threadIdx.x;
  int o = idx >> ibits;
  int i = idx & ((1 << ibits) - 1);
  int c = i >> 10;
  int il = i & 1023;
  float b = bw[idx];
  float scv = sc[idx];
  const float4* svp = (const float4*)sw;
  float4 s0 = svp[(size_t)idx * 2];
  float4 s1 = svp[(size_t)idx * 2 + 1];
  half_t* wrow = W + (size_t)o * ldw + c * 9216;
  wrow[il] = (half_t)b;
  half8 hv;
  hv[0] = (half_t)(s0.x * scv); hv[1] = (half_t)(s0.y * scv);
  hv[2] = (half_t)(s0.z * scv); hv[3] = (half_t)(s0.w * scv);
  hv[4] = (half_t)(s1.x * scv); hv[5] = (half_t)(s1.y * scv);
  hv[6] = (half_t)(s1.z * scv); hv[7] = (half_t)(s1.w * scv);
  *(half8*)&wrow[1024 + il * 8] = hv;
}

// ---------------- activation expansion: v -> [silu(v) | basis(v)[8]] fp16
// Optionally also copies v to xout (fuses the out=x residual baseline).
template <typename ST>
__global__ void expand_kernel(const ST* __restrict__ src, half_t* __restrict__ dst,
                              int Isrc, int i0, int dsub, int kexp,
                              float* __restrict__ xout) {
  int idx = blockIdx.x * 256 + threadIdx.x;
  int n = idx >> 10;
  int il = idx & 1023;
  float v = (float)src[(size_t)n * Isrc + i0 + il];
  float bs[8];
  bspline8u(v, bs);
  half_t* drow = dst + (size_t)n * kexp + (size_t)dsub * 9216;
  drow[il] = (half_t)(v / (1.0f + expf(-v)));
  half8 hb;
#pragma unroll
  for (int k = 0; k < 8; ++k) hb[k] = (half_t)bs[k];
  *(half8*)&drow[1024 + il * 8] = hb;
  if (xout) xout[(size_t)n * Isrc + il] = v;
}

// Single-pass expansion of all 4 layer-2 chunks (reads Hh once).
__global__ void expand4_kernel(const half_t* __restrict__ src, half_t* __restrict__ dst,
                               int ldk2) {
  int idx = blockIdx.x * 256 + threadIdx.x;      // over 4096*4096
  int n = idx >> 12;
  int il4 = idx & 4095;
  int c = il4 >> 10;
  int il = il4 & 1023;
  float v = (float)src[(size_t)n * 4096 + il4];
  float bs[8];
  bspline8u(v, bs);
  half_t* drow = dst + (size_t)n * ldk2 + (size_t)c * 9216;
  drow[il] = (half_t)(v / (1.0f + expf(-v)));
  half8 hb;
#pragma unroll
  for (int k = 0; k < 8; ++k) hb[k] = (half_t)bs[k];
  *(half8*)&drow[1024 + il * 8] = hb;
}

// ---------------- 8-phase 256x256 GEMM, SINGLE-BARRIER edition.
// Round-10's reg-double-buffer read-ahead spilled (128-arch-VGPR hard cap:
// 1 block/CU, acc=128 AGPR). This gets the same read/MFMA overlap with ZERO
// extra registers: drop the redundant 2nd barrier per phase. Phase =
// [barrier; MFMA(quad_i); stage_i; loads-for-quad_{i+1}; vmcnt(6)] — the
// ds_reads and gload issues execute while the MFMA pipe drains.
// Hazard ledger (epoch i = between barrier_i and barrier_{i+1}; stage_p
// drained at VM6_{p+3}, published barrier_{p+4}, readable epoch >= p+4;
// LOADS for quad q execute in epoch q-1 -> requirement q >= p+5):
//  stages p1..p8 -> first reads q = 6,7,9,9,10,11,13,13 vs p+5 =
//  6,7,8,9,10,11,12,13 — all satisfied. WAR margins (stage vs last ds_read
//  of old region) >= 2 barriers everywhere. Tail ladder 6,6,4,2,0,-,-,-
//  re-derived for the shifted epochs. Reg-WAR (loads overwriting in-flight
//  MFMA sources) is a bounded compiler-inserted-nop hazard.
#define STA(c, t, h)                                                          \
  {                                                                           \
    int r0_ = wid * 8 + (h) * 64;                                             \
    const half_t* g_ = Abase + (size_t)(r0_ + srow) * ldkA +                  \
                       (size_t)(t) * 64 + scol;                               \
    gload16(g_, &As[c][r0_ * 64]);                                            \
    gload16(g_ + (size_t)128 * ldkA, &As[c][(r0_ + 128) * 64]);               \
  }
#define STB(c, t, h)                                                          \
  {                                                                           \
    int r0_ = (wid >> 2) * 64 + (wid & 3) * 8 + (h) * 32;                     \
    const half_t* g_ = Bbase + (size_t)(r0_ + srow) * ldkB +                  \
                       (size_t)(t) * 64 + scol;                               \
    gload16(g_, &Bs[c][r0_ * 64]);                                            \
    gload16(g_ + (size_t)128 * ldkB, &Bs[c][(r0_ + 128) * 64]);               \
  }
#define LOADAF(c, mh)                                                         \
  _Pragma("unroll") for (int a = 0; a < 4; ++a) {                             \
    int row_ = wm * 128 + (mh) * 64 + a * 16 + (lane & 15);                   \
    _Pragma("unroll") for (int ks = 0; ks < 2; ++ks) {                        \
      int ch_ = (ks * 4 + (lane >> 4)) ^ (lane & 7);                          \
      af[a][ks] = *(const half8*)&As[c][row_ * 64 + ch_ * 8];                 \
    }                                                                         \
  }
#define LOADBF(c, nh, bfv)                                                    \
  _Pragma("unroll") for (int b = 0; b < 2; ++b) {                             \
    int row_ = wn * 64 + (nh) * 32 + b * 16 + (lane & 15);                    \
    _Pragma("unroll") for (int ks = 0; ks < 2; ++ks) {                        \
      int ch_ = (ks * 4 + (lane >> 4)) ^ (lane & 7);                          \
      bfv[b][ks] = *(const half8*)&Bs[c][row_ * 64 + ch_ * 8];                \
    }                                                                         \
  }
#define VM6 asm volatile("s_waitcnt vmcnt(6)" ::: "memory");
#define VM4 asm volatile("s_waitcnt vmcnt(4)" ::: "memory");
#define VM2 asm volatile("s_waitcnt vmcnt(2)" ::: "memory");
#define VM0 asm volatile("s_waitcnt vmcnt(0)" ::: "memory");
#define NOVM
// MFMA quad_i, then stage_i + loads for quad_{i+1}, then pacing wait.
#define DOPHASE(mh, nh, bfv, STAGE, LOADS, WAIT)                              \
  do {                                                                        \
    __builtin_amdgcn_s_barrier();                                             \
    __builtin_amdgcn_sched_barrier(0);                                        \
    __builtin_amdgcn_s_setprio(1);                                            \
    _Pragma("unroll") for (int ks = 0; ks < 2; ++ks)                          \
      _Pragma("unroll") for (int a = 0; a < 4; ++a)                           \
        _Pragma("unroll") for (int b = 0; b < 2; ++b)                         \
          acc[(mh) * 4 + a][(nh) * 2 + b] =                                   \
              __builtin_amdgcn_mfma_f32_16x16x32_f16(                         \
                  af[a][ks], bfv[b][ks], acc[(mh) * 4 + a][(nh) * 2 + b],     \
                  0, 0, 0);                                                   \
    __builtin_amdgcn_s_setprio(0);                                            \
    __builtin_amdgcn_sched_barrier(0);                                        \
    STAGE                                                                     \
    LOADS                                                                     \
    WAIT                                                                      \
  } while (0)

template <int MODE>
__global__ __launch_bounds__(512, 2) void gemm8_kernel(
    const half_t* __restrict__ A, const half_t* __restrict__ B,
    int ldkA, int ldkB, int kzLen,
    float* __restrict__ Cout, half_t* __restrict__ Hout, int ldc) {
  __shared__ __align__(16) half_t As[2][256 * 64];
  __shared__ __align__(16) half_t Bs[2][256 * 64];

  const int tid = threadIdx.x;
  const int wid = tid >> 6;
  const int lane = tid & 63;
  const int wm = wid >> 2;
  const int wn = wid & 3;

  const half_t* Abase = A + (size_t)blockIdx.x * 256 * ldkA +
                        (size_t)blockIdx.z * kzLen;
  const half_t* Bbase = B + (size_t)blockIdx.y * 256 * ldkB +
                        (size_t)blockIdx.z * kzLen;

  const int srow = lane >> 3;                    // row within 8-row region
  const int scol = ((lane & 7) ^ srow) * 8;      // pre-swizzled 16B chunk

  const int nt = kzLen >> 6;                     // K-tiles (BK=64), even, >=4

  f32x4 acc[8][4] = {};
  half8 af[4][2], bA[2][2], bB[2][2];

  // Prologue: tile0 complete + tile1 {A-h0, B-h0}; drain; barrier; then
  // pre-load quad-1 fragments (af0 c0, bA c0) before the loop's barrier.
  STA(0, 0, 0); STB(0, 0, 0); STB(0, 0, 1); STA(0, 0, 1);
  STA(1, 1, 0); STB(1, 1, 0);
  asm volatile("s_waitcnt vmcnt(0)" ::: "memory");
  __builtin_amdgcn_s_barrier();
  __builtin_amdgcn_sched_barrier(0);
  LOADAF(0, 0)
  LOADBF(0, 0, bA)

  for (int i = 0; i < (nt >> 1) - 1; ++i) {
    const int t = 2 * i;
    DOPHASE(0, 0, bA, { STB(1, t + 1, 1); }, { LOADBF(0, 1, bB) },              VM6);
    DOPHASE(0, 1, bB, { STA(1, t + 1, 1); }, { LOADAF(0, 1) },                  VM6);
    DOPHASE(1, 1, bB, { STA(0, t + 2, 0); }, {},                                VM6);
    DOPHASE(1, 0, bA, { STB(0, t + 2, 0); }, { LOADAF(1, 0) LOADBF(1, 0, bA) }, VM6);
    DOPHASE(0, 0, bA, { STB(0, t + 2, 1); }, { LOADBF(1, 1, bB) },              VM6);
    DOPHASE(0, 1, bB, { STA(0, t + 2, 1); }, { LOADAF(1, 1) },                  VM6);
    DOPHASE(1, 1, bB, { STA(1, t + 3, 0); }, {},                                VM6);
    DOPHASE(1, 0, bA, { STB(1, t + 3, 0); }, { LOADAF(0, 0) LOADBF(0, 0, bA) }, VM6);
  }
  {
    const int t = nt - 2;  // tail: stage only t+1's remaining halves
    DOPHASE(0, 0, bA, { STB(1, t + 1, 1); }, { LOADBF(0, 1, bB) },              VM6);
    DOPHASE(0, 1, bB, { STA(1, t + 1, 1); }, { LOADAF(0, 1) },                  VM6);
    DOPHASE(1, 1, bB, {},                    {},                                VM4);
    DOPHASE(1, 0, bA, {},                    { LOADAF(1, 0) LOADBF(1, 0, bA) }, VM2);
    DOPHASE(0, 0, bA, {},                    { LOADBF(1, 1, bB) },              VM0);
    DOPHASE(0, 1, bB, {},                    { LOADAF(1, 1) },                  NOVM);
    DOPHASE(1, 1, bB, {},                    {},                                NOVM);
    DOPHASE(1, 0, bA, {},                    {},                                NOVM);
  }

  const int r_lo = (lane >> 4) << 2;
  const int col0 = (int)blockIdx.y * 256 + wn * 64 + (lane & 15);
  const int row00 = (int)blockIdx.x * 256 + wm * 128 + r_lo;
#pragma unroll
  for (int mf = 0; mf < 8; ++mf)
#pragma unroll
    for (int nf = 0; nf < 4; ++nf)
#pragma unroll
      for (int j = 0; j < 4; ++j) {
        float v = acc[mf][nf][j];
        size_t off = (size_t)(row00 + mf * 16 + j) * ldc + col0 + nf * 16;
        if constexpr (MODE == 0) {
          v = 0.5f * v * (1.0f + erff(v * 0.70710678118654752f));
          Hout[off] = (half_t)v;
        } else {
          atomicAdd(&Cout[off], v);
        }
      }
}

extern "C" void kernel_launch(void* const* d_in, const int* in_sizes, int n_in,
                              void* d_out, int out_size, void* d_ws, size_t ws_size,
                              hipStream_t stream) {
  const float* x   = (const float*)d_in[0];
  const float* bw1 = (const float*)d_in[1];
  const float* sw1 = (const float*)d_in[2];
  const float* sc1 = (const float*)d_in[3];
  const float* bw2 = (const float*)d_in[4];
  const float* sw2 = (const float*)d_in[5];
  const float* sc2 = (const float*)d_in[6];
  float* out = (float*)d_out;

  const int LDK1 = 9216 + 64;
  const int LDK2 = 36864 + 64;
  const int LDK2H = 18432 + 64;

  half_t* Wbuf = (half_t*)d_ws;
  const size_t W_HALVES  = (size_t)4096 * LDK1;
  const size_t AF_HALVES = (size_t)4096 * LDK2;
  const size_t A2_HALVES = (size_t)4096 * LDK2H;
  const size_t A1_HALVES = (size_t)4096 * LDK1;
  const size_t HH_HALVES = (size_t)4096 * 4096;
  int abuf_chunks = 1;
  if (ws_size >= (W_HALVES + AF_HALVES + HH_HALVES) * sizeof(half_t))
    abuf_chunks = 4;
  else if (ws_size >= (W_HALVES + A2_HALVES + HH_HALVES) * sizeof(half_t))
    abuf_chunks = 2;
  half_t* Abuf = Wbuf + W_HALVES;
  half_t* Hh   = Abuf + (abuf_chunks == 4 ? AF_HALVES
                         : abuf_chunks == 2 ? A2_HALVES : A1_HALVES);

  const int T = 256;
  const int NB = (4096 * 1024) / T;

  // ---- layer 1 (expand1 also writes out = x, the residual baseline) ----
  wconv_kernel<<<NB, T, 0, stream>>>(bw1, sw1, sc1, Wbuf, 10, LDK1);
  expand_kernel<float><<<NB, T, 0, stream>>>(x, Abuf, 1024, 0, 0, LDK1, out);
  gemm8_kernel<0><<<dim3(16, 16, 1), 512, 0, stream>>>(
      Abuf, Wbuf, LDK1, LDK1, 9216, nullptr, Hh, 4096);

  // ---- layer 2: W2 rows [o][LDK2], data K-contiguous in [0,36864) ----
  wconv_kernel<<<NB, T, 0, stream>>>(bw2, sw2, sc2, Wbuf, 12, LDK2);
  if (abuf_chunks == 4) {
    expand4_kernel<<<4 * NB, T, 0, stream>>>(Hh, Abuf, LDK2);
    gemm8_kernel<4><<<dim3(16, 4, 4), 512, 0, stream>>>(
        Abuf, Wbuf, LDK2, LDK2, 9216, out, nullptr, 1024);
  } else if (abuf_chunks == 2) {
    for (int c = 0; c < 2; ++c) {
      expand_kernel<half_t><<<NB, T, 0, stream>>>(Hh, Abuf, 4096, c * 2048, 0, LDK2H, nullptr);
      expand_kernel<half_t><<<NB, T, 0, stream>>>(Hh, Abuf, 4096, c * 2048 + 1024, 1, LDK2H, nullptr);
      gemm8_kernel<4><<<dim3(16, 4, 4), 512, 0, stream>>>(
          Abuf, Wbuf + (size_t)c * 18432, LDK2H, LDK2, 4608, out, nullptr, 1024);
    }
  } else {
    for (int c = 0; c < 4; ++c) {
      expand_kernel<half_t><<<NB, T, 0, stream>>>(Hh, Abuf, 4096, c * 1024, 0, LDK1, nullptr);
      gemm8_kernel<4><<<dim3(16, 4, 4), 512, 0, stream>>>(
          Abuf, Wbuf + (size_t)c * 9216, LDK1, LDK2, 2304, out, nullptr, 1024);
    }
  }
}

// Round 12
// 864.874 us; speedup vs baseline: 1.9427x; 1.0181x over previous
//
#include <hip/hip_runtime.h>
#include <hip/hip_fp16.h>

typedef _Float16 half_t;
typedef __attribute__((ext_vector_type(8))) _Float16 half8;
typedef __attribute__((ext_vector_type(4))) _Float16 half4;
typedef __attribute__((ext_vector_type(4))) float f32x4;

#define AS1 __attribute__((address_space(1)))
#define AS3 __attribute__((address_space(3)))

__device__ __forceinline__ void gload16(const half_t* g, half_t* l) {
  __builtin_amdgcn_global_load_lds((const AS1 void*)g, (AS3 void*)l, 16, 0, 0);
}

// ---------------- B-spline basis, UNIFORM grid (h=0.4, knots (j-3)*0.4-1).
__device__ __forceinline__ void bspline8u(float x, float out[8]) {
  float g[12];
#pragma unroll
  for (int j = 0; j < 12; ++j) g[j] = (float)(j - 3) * 0.4f - 1.0f;
  float b[11];
#pragma unroll
  for (int j = 0; j < 11; ++j)
    b[j] = (x >= g[j] && x < g[j + 1]) ? 1.0f : 0.0f;
#pragma unroll
  for (int k = 1; k <= 3; ++k) {
#pragma unroll
    for (int j = 0; j + k < 11; ++j) {
      float rl = 1.0f / (g[j + k] - g[j]);         // constant-folded
      float rr = 1.0f / (g[j + k + 1] - g[j + 1]); // constant-folded
      b[j] = ((x - g[j]) * rl) * b[j] + ((g[j + k + 1] - x) * rr) * b[j + 1];
    }
  }
#pragma unroll
  for (int j = 0; j < 8; ++j) out[j] = b[j];
}

// ---------------- weight conversion: fp32 (base,spline*scaler) -> fp16
__global__ void wconv_kernel(const float* __restrict__ bw, const float* __restrict__ sw,
                             const float* __restrict__ sc, half_t* __restrict__ W,
                             int ibits, int ldw) {
  int idx = blockIdx.x * 256 + threadIdx.x;
  int o = idx >> ibits;
  int i = idx & ((1 << ibits) - 1);
  int c = i >> 10;
  int il = i & 1023;
  float b = bw[idx];
  float scv = sc[idx];
  const float4* svp = (const float4*)sw;
  float4 s0 = svp[(size_t)idx * 2];
  float4 s1 = svp[(size_t)idx * 2 + 1];
  half_t* wrow = W + (size_t)o * ldw + c * 9216;
  wrow[il] = (half_t)b;
  half8 hv;
  hv[0] = (half_t)(s0.x * scv); hv[1] = (half_t)(s0.y * scv);
  hv[2] = (half_t)(s0.z * scv); hv[3] = (half_t)(s0.w * scv);
  hv[4] = (half_t)(s1.x * scv); hv[5] = (half_t)(s1.y * scv);
  hv[6] = (half_t)(s1.z * scv); hv[7] = (half_t)(s1.w * scv);
  *(half8*)&wrow[1024 + il * 8] = hv;
}

// ---------------- layer-1 expansion, vectorized x4 (float4 read), fused
// residual copy out=x. 4096x1024 elems / 4 per thread.
__global__ void expand1v4_kernel(const float* __restrict__ x, half_t* __restrict__ dst,
                                 int kexp, float* __restrict__ xout) {
  int idx = blockIdx.x * 256 + threadIdx.x;      // over 4096*256
  int n = idx >> 8;
  int i4 = (idx & 255) * 4;
  float4 v = *(const float4*)&x[(size_t)n * 1024 + i4];
  half_t* drow = dst + (size_t)n * kexp;
  float vv[4] = {v.x, v.y, v.z, v.w};
  half4 bh;
#pragma unroll
  for (int j = 0; j < 4; ++j) {
    float bs[8];
    bspline8u(vv[j], bs);
    bh[j] = (half_t)(vv[j] / (1.0f + expf(-vv[j])));
    half8 hb;
#pragma unroll
    for (int k = 0; k < 8; ++k) hb[k] = (half_t)bs[k];
    *(half8*)&drow[1024 + (i4 + j) * 8] = hb;
  }
  *(half4*)&drow[i4] = bh;
  *(float4*)&xout[(size_t)n * 1024 + i4] = v;
}

// ---------------- scalar expansion (fallback modes only)
template <typename ST>
__global__ void expand_kernel(const ST* __restrict__ src, half_t* __restrict__ dst,
                              int Isrc, int i0, int dsub, int kexp) {
  int idx = blockIdx.x * 256 + threadIdx.x;
  int n = idx >> 10;
  int il = idx & 1023;
  float v = (float)src[(size_t)n * Isrc + i0 + il];
  float bs[8];
  bspline8u(v, bs);
  half_t* drow = dst + (size_t)n * kexp + (size_t)dsub * 9216;
  drow[il] = (half_t)(v / (1.0f + expf(-v)));
  half8 hb;
#pragma unroll
  for (int k = 0; k < 8; ++k) hb[k] = (half_t)bs[k];
  *(half8*)&drow[1024 + il * 8] = hb;
}

// Single-pass layer-2 expansion, vectorized x8 (half8 read of Hh; half8 base
// write; 64B-contiguous spline writes). 4096x4096 elems / 8 per thread.
__global__ void expand4v8_kernel(const half_t* __restrict__ src, half_t* __restrict__ dst,
                                 int ldk2) {
  int idx = blockIdx.x * 256 + threadIdx.x;      // over 4096*512
  int n = idx >> 9;
  int e8 = (idx & 511) * 8;
  int c = e8 >> 10;
  int il = e8 & 1023;
  half8 hv = *(const half8*)&src[(size_t)n * 4096 + e8];
  half_t* drow = dst + (size_t)n * ldk2 + (size_t)c * 9216;
  half8 bh;
#pragma unroll
  for (int j = 0; j < 8; ++j) {
    float v = (float)hv[j];
    float bs[8];
    bspline8u(v, bs);
    bh[j] = (half_t)(v / (1.0f + expf(-v)));
    half8 hb;
#pragma unroll
    for (int k = 0; k < 8; ++k) hb[k] = (half_t)bs[k];
    *(half8*)&drow[1024 + (il + j) * 8] = hb;
  }
  *(half8*)&drow[il] = bh;
}

// ---------------- 8-phase 256x256 GEMM — round-6 schedule + VM8/respread.
// Proven-best structure (345us gemm2; all 4 tested deviations regress).
// Change vs round-6: p8's STB moved to p7 (per-phase gload issues become
// {2,2,2,2,2,2,4,0}) and all steady waits vmcnt(8). Ledger: every
// stage->read edge has EXACTLY 8 loads issued between stage and the wait
// preceding the read (As0h0 p3->p1':10; Bs0h0 p4->p1':8; Bs0h1 p5->p2':8;
// As0h1 p6->p3':8; As1h0,Bs1h0 p7->p5':8; Bs1h1 p1->p6:8; As1h1 p2->p7:8)
// -> identical publication safety, but each phase now stalls only on
// 7-phase-old loads (VM6 demanded 3-phase-old). WAR margins unchanged
// (p7's overwrites: last readers at p5, >=2 barriers). Tail ladder
// 8,8,8,4,2,0,-,- re-derived exactly (p4:VM4 retires prev-p7's 4; p5:VM2
// retires tail-p1; p6:VM0 retires tail-p2).
#define STA(c, t, h)                                                          \
  {                                                                           \
    int r0_ = wid * 8 + (h) * 64;                                             \
    const half_t* g_ = Abase + (size_t)(r0_ + srow) * ldkA +                  \
                       (size_t)(t) * 64 + scol;                               \
    gload16(g_, &As[c][r0_ * 64]);                                            \
    gload16(g_ + (size_t)128 * ldkA, &As[c][(r0_ + 128) * 64]);               \
  }
#define STB(c, t, h)                                                          \
  {                                                                           \
    int r0_ = (wid >> 2) * 64 + (wid & 3) * 8 + (h) * 32;                     \
    const half_t* g_ = Bbase + (size_t)(r0_ + srow) * ldkB +                  \
                       (size_t)(t) * 64 + scol;                               \
    gload16(g_, &Bs[c][r0_ * 64]);                                            \
    gload16(g_ + (size_t)128 * ldkB, &Bs[c][(r0_ + 128) * 64]);               \
  }
#define LOADAF(c, mh)                                                         \
  _Pragma("unroll") for (int a = 0; a < 4; ++a) {                             \
    int row_ = wm * 128 + (mh) * 64 + a * 16 + (lane & 15);                   \
    _Pragma("unroll") for (int ks = 0; ks < 2; ++ks) {                        \
      int ch_ = (ks * 4 + (lane >> 4)) ^ (lane & 7);                          \
      af[a][ks] = *(const half8*)&As[c][row_ * 64 + ch_ * 8];                 \
    }                                                                         \
  }
#define LOADBF(c, nh, bfv)                                                    \
  _Pragma("unroll") for (int b = 0; b < 2; ++b) {                             \
    int row_ = wn * 64 + (nh) * 32 + b * 16 + (lane & 15);                    \
    _Pragma("unroll") for (int ks = 0; ks < 2; ++ks) {                        \
      int ch_ = (ks * 4 + (lane >> 4)) ^ (lane & 7);                          \
      bfv[b][ks] = *(const half8*)&Bs[c][row_ * 64 + ch_ * 8];                \
    }                                                                         \
  }
#define VM8 asm volatile("s_waitcnt vmcnt(8)" ::: "memory");
#define VM4 asm volatile("s_waitcnt vmcnt(4)" ::: "memory");
#define VM2 asm volatile("s_waitcnt vmcnt(2)" ::: "memory");
#define VM0 asm volatile("s_waitcnt vmcnt(0)" ::: "memory");
#define NOVM
#define DOPHASE(mh, nh, bfv, LOADS, STAGE, WAIT)                              \
  do {                                                                        \
    LOADS                                                                     \
    STAGE                                                                     \
    WAIT                                                                      \
    __builtin_amdgcn_s_barrier();                                             \
    __builtin_amdgcn_sched_barrier(0);                                        \
    __builtin_amdgcn_s_setprio(1);                                            \
    _Pragma("unroll") for (int ks = 0; ks < 2; ++ks)                          \
      _Pragma("unroll") for (int a = 0; a < 4; ++a)                           \
        _Pragma("unroll") for (int b = 0; b < 2; ++b)                         \
          acc[(mh) * 4 + a][(nh) * 2 + b] =                                   \
              __builtin_amdgcn_mfma_f32_16x16x32_f16(                         \
                  af[a][ks], bfv[b][ks], acc[(mh) * 4 + a][(nh) * 2 + b],     \
                  0, 0, 0);                                                   \
    __builtin_amdgcn_s_setprio(0);                                            \
    __builtin_amdgcn_s_barrier();                                             \
    __builtin_amdgcn_sched_barrier(0);                                        \
  } while (0)

template <int MODE>
__global__ __launch_bounds__(512, 2) void gemm8_kernel(
    const half_t* __restrict__ A, const half_t* __restrict__ B,
    int ldkA, int ldkB, int kzLen,
    float* __restrict__ Cout, half_t* __restrict__ Hout, int ldc) {
  __shared__ __align__(16) half_t As[2][256 * 64];
  __shared__ __align__(16) half_t Bs[2][256 * 64];

  const int tid = threadIdx.x;
  const int wid = tid >> 6;
  const int lane = tid & 63;
  const int wm = wid >> 2;
  const int wn = wid & 3;

  const half_t* Abase = A + (size_t)blockIdx.x * 256 * ldkA +
                        (size_t)blockIdx.z * kzLen;
  const half_t* Bbase = B + (size_t)blockIdx.y * 256 * ldkB +
                        (size_t)blockIdx.z * kzLen;

  const int srow = lane >> 3;                    // row within 8-row region
  const int scol = ((lane & 7) ^ srow) * 8;      // pre-swizzled 16B chunk

  const int nt = kzLen >> 6;                     // K-tiles (BK=64), even, >=4

  f32x4 acc[8][4] = {};
  half8 af[4][2], bA[2][2], bB[2][2];

  // Prologue: tile0 complete + tile1 {A-h0, B-h0}; drain; barrier.
  STA(0, 0, 0); STB(0, 0, 0); STB(0, 0, 1); STA(0, 0, 1);
  STA(1, 1, 0); STB(1, 1, 0);
  asm volatile("s_waitcnt vmcnt(0)" ::: "memory");
  __builtin_amdgcn_s_barrier();
  __builtin_amdgcn_sched_barrier(0);

  for (int i = 0; i < (nt >> 1) - 1; ++i) {
    const int t = 2 * i;
    DOPHASE(0, 0, bA, { LOADAF(0, 0) LOADBF(0, 0, bA) }, { STB(1, t + 1, 1); }, VM8);
    DOPHASE(0, 1, bB, { LOADBF(0, 1, bB) },              { STA(1, t + 1, 1); }, VM8);
    DOPHASE(1, 1, bB, { LOADAF(0, 1) },                  { STA(0, t + 2, 0); }, VM8);
    DOPHASE(1, 0, bA, {},                                { STB(0, t + 2, 0); }, VM8);
    DOPHASE(0, 0, bA, { LOADAF(1, 0) LOADBF(1, 0, bA) }, { STB(0, t + 2, 1); }, VM8);
    DOPHASE(0, 1, bB, { LOADBF(1, 1, bB) },              { STA(0, t + 2, 1); }, VM8);
    DOPHASE(1, 1, bB, { LOADAF(1, 1) },                  { STA(1, t + 3, 0); STB(1, t + 3, 0); }, VM8);
    DOPHASE(1, 0, bA, {},                                {},                    VM8);
  }
  {
    const int t = nt - 2;  // tail: stages only t+1's remaining halves
    DOPHASE(0, 0, bA, { LOADAF(0, 0) LOADBF(0, 0, bA) }, { STB(1, t + 1, 1); }, VM8);
    DOPHASE(0, 1, bB, { LOADBF(0, 1, bB) },              { STA(1, t + 1, 1); }, VM8);
    DOPHASE(1, 1, bB, { LOADAF(0, 1) },                  {},                    VM8);
    DOPHASE(1, 0, bA, {},                                {},                    VM4);
    DOPHASE(0, 0, bA, { LOADAF(1, 0) LOADBF(1, 0, bA) }, {},                    VM2);
    DOPHASE(0, 1, bB, { LOADBF(1, 1, bB) },              {},                    VM0);
    DOPHASE(1, 1, bB, { LOADAF(1, 1) },                  {},                    NOVM);
    DOPHASE(1, 0, bA, {},                                {},                    NOVM);
  }

  const int r_lo = (lane >> 4) << 2;
  const int col0 = (int)blockIdx.y * 256 + wn * 64 + (lane & 15);
  const int row00 = (int)blockIdx.x * 256 + wm * 128 + r_lo;
#pragma unroll
  for (int mf = 0; mf < 8; ++mf)
#pragma unroll
    for (int nf = 0; nf < 4; ++nf)
#pragma unroll
      for (int j = 0; j < 4; ++j) {
        float v = acc[mf][nf][j];
        size_t off = (size_t)(row00 + mf * 16 + j) * ldc + col0 + nf * 16;
        if constexpr (MODE == 0) {
          v = 0.5f * v * (1.0f + erff(v * 0.70710678118654752f));
          Hout[off] = (half_t)v;
        } else {
          atomicAdd(&Cout[off], v);
        }
      }
}

extern "C" void kernel_launch(void* const* d_in, const int* in_sizes, int n_in,
                              void* d_out, int out_size, void* d_ws, size_t ws_size,
                              hipStream_t stream) {
  const float* x   = (const float*)d_in[0];
  const float* bw1 = (const float*)d_in[1];
  const float* sw1 = (const float*)d_in[2];
  const float* sc1 = (const float*)d_in[3];
  const float* bw2 = (const float*)d_in[4];
  const float* sw2 = (const float*)d_in[5];
  const float* sc2 = (const float*)d_in[6];
  float* out = (float*)d_out;

  const int LDK1 = 9216 + 64;
  const int LDK2 = 36864 + 64;
  const int LDK2H = 18432 + 64;

  half_t* Wbuf = (half_t*)d_ws;
  const size_t W_HALVES  = (size_t)4096 * LDK1;
  const size_t AF_HALVES = (size_t)4096 * LDK2;
  const size_t A2_HALVES = (size_t)4096 * LDK2H;
  const size_t A1_HALVES = (size_t)4096 * LDK1;
  const size_t HH_HALVES = (size_t)4096 * 4096;
  int abuf_chunks = 1;
  if (ws_size >= (W_HALVES + AF_HALVES + HH_HALVES) * sizeof(half_t))
    abuf_chunks = 4;
  else if (ws_size >= (W_HALVES + A2_HALVES + HH_HALVES) * sizeof(half_t))
    abuf_chunks = 2;
  half_t* Abuf = Wbuf + W_HALVES;
  half_t* Hh   = Abuf + (abuf_chunks == 4 ? AF_HALVES
                         : abuf_chunks == 2 ? A2_HALVES : A1_HALVES);

  const int T = 256;
  const int NB = (4096 * 1024) / T;

  // ---- layer 1 (expand1v4 also writes out = x, the residual baseline) ----
  wconv_kernel<<<NB, T, 0, stream>>>(bw1, sw1, sc1, Wbuf, 10, LDK1);
  expand1v4_kernel<<<NB / 4, T, 0, stream>>>(x, Abuf, LDK1, out);
  gemm8_kernel<0><<<dim3(16, 16, 1), 512, 0, stream>>>(
      Abuf, Wbuf, LDK1, LDK1, 9216, nullptr, Hh, 4096);

  // ---- layer 2: W2 rows [o][LDK2], data K-contiguous in [0,36864) ----
  wconv_kernel<<<NB, T, 0, stream>>>(bw2, sw2, sc2, Wbuf, 12, LDK2);
  if (abuf_chunks == 4) {
    expand4v8_kernel<<<NB / 2, T, 0, stream>>>(Hh, Abuf, LDK2);
    gemm8_kernel<4><<<dim3(16, 4, 4), 512, 0, stream>>>(
        Abuf, Wbuf, LDK2, LDK2, 9216, out, nullptr, 1024);
  } else if (abuf_chunks == 2) {
    for (int c = 0; c < 2; ++c) {
      expand_kernel<half_t><<<NB, T, 0, stream>>>(Hh, Abuf, 4096, c * 2048, 0, LDK2H);
      expand_kernel<half_t><<<NB, T, 0, stream>>>(Hh, Abuf, 4096, c * 2048 + 1024, 1, LDK2H);
      gemm8_kernel<4><<<dim3(16, 4, 4), 512, 0, stream>>>(
          Abuf, Wbuf + (size_t)c * 18432, LDK2H, LDK2, 4608, out, nullptr, 1024);
    }
  } else {
    for (int c = 0; c < 4; ++c) {
      expand_kernel<half_t><<<NB, T, 0, stream>>>(Hh, Abuf, 4096, c * 1024, 0, LDK1);
      gemm8_kernel<4><<<dim3(16, 4, 4), 512, 0, stream>>>(
          Abuf, Wbuf + (size_t)c * 9216, LDK1, LDK2, 2304, out, nullptr, 1024);
    }
  }
}

// Round 13
// 798.891 us; speedup vs baseline: 2.1032x; 1.0826x over previous
//
#include <hip/hip_runtime.h>
#include <hip/hip_fp16.h>

typedef _Float16 half_t;
typedef __attribute__((ext_vector_type(8))) _Float16 half8;
typedef __attribute__((ext_vector_type(4))) float f32x4;

#define AS1 __attribute__((address_space(1)))
#define AS3 __attribute__((address_space(3)))

__device__ __forceinline__ void gload16(const half_t* g, half_t* l) {
  __builtin_amdgcn_global_load_lds((const AS1 void*)g, (AS3 void*)l, 16, 0, 0);
}

// ---------------- B-spline basis, UNIFORM grid (h=0.4, knots (j-3)*0.4-1).
__device__ __forceinline__ void bspline8u(float x, float out[8]) {
  float g[12];
#pragma unroll
  for (int j = 0; j < 12; ++j) g[j] = (float)(j - 3) * 0.4f - 1.0f;
  float b[11];
#pragma unroll
  for (int j = 0; j < 11; ++j)
    b[j] = (x >= g[j] && x < g[j + 1]) ? 1.0f : 0.0f;
#pragma unroll
  for (int k = 1; k <= 3; ++k) {
#pragma unroll
    for (int j = 0; j + k < 11; ++j) {
      float rl = 1.0f / (g[j + k] - g[j]);         // constant-folded
      float rr = 1.0f / (g[j + k + 1] - g[j + 1]); // constant-folded
      b[j] = ((x - g[j]) * rl) * b[j] + ((g[j + k + 1] - x) * rr) * b[j + 1];
    }
  }
#pragma unroll
  for (int j = 0; j < 8; ++j) out[j] = b[j];
}

// ---------------- weight conversion: fp32 (base,spline*scaler) -> fp16
__global__ void wconv_kernel(const float* __restrict__ bw, const float* __restrict__ sw,
                             const float* __restrict__ sc, half_t* __restrict__ W,
                             int ibits, int ldw) {
  int idx = blockIdx.x * 256 + threadIdx.x;
  int o = idx >> ibits;
  int i = idx & ((1 << ibits) - 1);
  int c = i >> 10;
  int il = i & 1023;
  float b = bw[idx];
  float scv = sc[idx];
  const float4* svp = (const float4*)sw;
  float4 s0 = svp[(size_t)idx * 2];
  float4 s1 = svp[(size_t)idx * 2 + 1];
  half_t* wrow = W + (size_t)o * ldw + c * 9216;
  wrow[il] = (half_t)b;
  half8 hv;
  hv[0] = (half_t)(s0.x * scv); hv[1] = (half_t)(s0.y * scv);
  hv[2] = (half_t)(s0.z * scv); hv[3] = (half_t)(s0.w * scv);
  hv[4] = (half_t)(s1.x * scv); hv[5] = (half_t)(s1.y * scv);
  hv[6] = (half_t)(s1.z * scv); hv[7] = (half_t)(s1.w * scv);
  *(half8*)&wrow[1024 + il * 8] = hv;
}

// ---------------- activation expansion: v -> [silu(v) | basis(v)[8]] fp16
// Optionally also copies v to xout (fuses the out=x residual baseline).
// Scalar layout: lane-adjacent 16B spline stores = fully coalesced (the
// round-12 per-thread-vectorized variant de-coalesced these; reverted).
template <typename ST>
__global__ void expand_kernel(const ST* __restrict__ src, half_t* __restrict__ dst,
                              int Isrc, int i0, int dsub, int kexp,
                              float* __restrict__ xout) {
  int idx = blockIdx.x * 256 + threadIdx.x;
  int n = idx >> 10;
  int il = idx & 1023;
  float v = (float)src[(size_t)n * Isrc + i0 + il];
  float bs[8];
  bspline8u(v, bs);
  half_t* drow = dst + (size_t)n * kexp + (size_t)dsub * 9216;
  drow[il] = (half_t)(v / (1.0f + expf(-v)));
  half8 hb;
#pragma unroll
  for (int k = 0; k < 8; ++k) hb[k] = (half_t)bs[k];
  *(half8*)&drow[1024 + il * 8] = hb;
  if (xout) xout[(size_t)n * Isrc + il] = v;
}

// Single-pass expansion of all 4 layer-2 chunks (reads Hh once).
__global__ void expand4_kernel(const half_t* __restrict__ src, half_t* __restrict__ dst,
                               int ldk2) {
  int idx = blockIdx.x * 256 + threadIdx.x;      // over 4096*4096
  int n = idx >> 12;
  int il4 = idx & 4095;
  int c = il4 >> 10;
  int il = il4 & 1023;
  float v = (float)src[(size_t)n * 4096 + il4];
  float bs[8];
  bspline8u(v, bs);
  half_t* drow = dst + (size_t)n * ldk2 + (size_t)c * 9216;
  drow[il] = (half_t)(v / (1.0f + expf(-v)));
  half8 hb;
#pragma unroll
  for (int k = 0; k < 8; ++k) hb[k] = (half_t)bs[k];
  *(half8*)&drow[1024 + il * 8] = hb;
}

// ---------------- 8-phase 256x256 GEMM — the proven-best schedule.
// Gray-code quadrant order with persistent frag regs (24 ds_read_b128 per
// K-tile/wave), per-phase vmcnt(6) pacing, 2 barriers/phase, peeled tail
// with exact counted waits 6,6,6,6,4,2,0,0. Schedule-variant bracket
// (rounds 6-12): this config 345us; VM8 358; even-reads 369; 2-point-vmcnt
// 385; 1-barrier 395; reg-dbuf spills. Staging-throughput arithmetic puts
// all configs at the same ~7-8 TB/s LLC-supply wall; this one maximizes
// arithmetic intensity within the 160KiB-LDS / 256-reg envelope.
#define STA(c, t, h)                                                          \
  {                                                                           \
    int r0_ = wid * 8 + (h) * 64;                                             \
    const half_t* g_ = Abase + (size_t)(r0_ + srow) * ldkA +                  \
                       (size_t)(t) * 64 + scol;                               \
    gload16(g_, &As[c][r0_ * 64]);                                            \
    gload16(g_ + (size_t)128 * ldkA, &As[c][(r0_ + 128) * 64]);               \
  }
#define STB(c, t, h)                                                          \
  {                                                                           \
    int r0_ = (wid >> 2) * 64 + (wid & 3) * 8 + (h) * 32;                     \
    const half_t* g_ = Bbase + (size_t)(r0_ + srow) * ldkB +                  \
                       (size_t)(t) * 64 + scol;                               \
    gload16(g_, &Bs[c][r0_ * 64]);                                            \
    gload16(g_ + (size_t)128 * ldkB, &Bs[c][(r0_ + 128) * 64]);               \
  }
#define LOADAF(c, mh)                                                         \
  _Pragma("unroll") for (int a = 0; a < 4; ++a) {                             \
    int row_ = wm * 128 + (mh) * 64 + a * 16 + (lane & 15);                   \
    _Pragma("unroll") for (int ks = 0; ks < 2; ++ks) {                        \
      int ch_ = (ks * 4 + (lane >> 4)) ^ (lane & 7);                          \
      af[a][ks] = *(const half8*)&As[c][row_ * 64 + ch_ * 8];                 \
    }                                                                         \
  }
#define LOADBF(c, nh, bfv)                                                    \
  _Pragma("unroll") for (int b = 0; b < 2; ++b) {                             \
    int row_ = wn * 64 + (nh) * 32 + b * 16 + (lane & 15);                    \
    _Pragma("unroll") for (int ks = 0; ks < 2; ++ks) {                        \
      int ch_ = (ks * 4 + (lane >> 4)) ^ (lane & 7);                          \
      bfv[b][ks] = *(const half8*)&Bs[c][row_ * 64 + ch_ * 8];                \
    }                                                                         \
  }
#define DOPHASE(W, mh, nh, bfv, LOADS, STAGE)                                 \
  do {                                                                        \
    LOADS                                                                     \
    STAGE                                                                     \
    asm volatile("s_waitcnt vmcnt(" #W ")" ::: "memory");                     \
    __builtin_amdgcn_s_barrier();                                             \
    __builtin_amdgcn_sched_barrier(0);                                        \
    __builtin_amdgcn_s_setprio(1);                                            \
    _Pragma("unroll") for (int ks = 0; ks < 2; ++ks)                          \
      _Pragma("unroll") for (int a = 0; a < 4; ++a)                           \
        _Pragma("unroll") for (int b = 0; b < 2; ++b)                         \
          acc[(mh) * 4 + a][(nh) * 2 + b] =                                   \
              __builtin_amdgcn_mfma_f32_16x16x32_f16(                         \
                  af[a][ks], bfv[b][ks], acc[(mh) * 4 + a][(nh) * 2 + b],     \
                  0, 0, 0);                                                   \
    __builtin_amdgcn_s_setprio(0);                                            \
    __builtin_amdgcn_s_barrier();                                             \
    __builtin_amdgcn_sched_barrier(0);                                        \
  } while (0)

template <int MODE>
__global__ __launch_bounds__(512, 2) void gemm8_kernel(
    const half_t* __restrict__ A, const half_t* __restrict__ B,
    int ldkA, int ldkB, int kzLen,
    float* __restrict__ Cout, half_t* __restrict__ Hout, int ldc) {
  __shared__ __align__(16) half_t As[2][256 * 64];
  __shared__ __align__(16) half_t Bs[2][256 * 64];

  const int tid = threadIdx.x;
  const int wid = tid >> 6;
  const int lane = tid & 63;
  const int wm = wid >> 2;
  const int wn = wid & 3;

  const half_t* Abase = A + (size_t)blockIdx.x * 256 * ldkA +
                        (size_t)blockIdx.z * kzLen;
  const half_t* Bbase = B + (size_t)blockIdx.y * 256 * ldkB +
                        (size_t)blockIdx.z * kzLen;

  const int srow = lane >> 3;                    // row within 8-row region
  const int scol = ((lane & 7) ^ srow) * 8;      // pre-swizzled 16B chunk

  const int nt = kzLen >> 6;                     // K-tiles (BK=64), even, >=4

  f32x4 acc[8][4] = {};
  half8 af[4][2], bA[2][2], bB[2][2];

  // Prologue: tile0 complete + tile1 {Am0,Bn0}; drain; barrier.
  STA(0, 0, 0); STB(0, 0, 0); STB(0, 0, 1); STA(0, 0, 1);
  STA(1, 1, 0); STB(1, 1, 0);
  asm volatile("s_waitcnt vmcnt(0)" ::: "memory");
  __builtin_amdgcn_s_barrier();
  __builtin_amdgcn_sched_barrier(0);

  for (int i = 0; i < (nt >> 1) - 1; ++i) {
    const int t = 2 * i;
    DOPHASE(6, 0, 0, bA, { LOADAF(0, 0) LOADBF(0, 0, bA) }, { STB(1, t + 1, 1); });
    DOPHASE(6, 0, 1, bB, { LOADBF(0, 1, bB) },              { STA(1, t + 1, 1); });
    DOPHASE(6, 1, 1, bB, { LOADAF(0, 1) },                  { STA(0, t + 2, 0); });
    DOPHASE(6, 1, 0, bA, {},                                { STB(0, t + 2, 0); });
    DOPHASE(6, 0, 0, bA, { LOADAF(1, 0) LOADBF(1, 0, bA) }, { STB(0, t + 2, 1); });
    DOPHASE(6, 0, 1, bB, { LOADBF(1, 1, bB) },              { STA(0, t + 2, 1); });
    DOPHASE(6, 1, 1, bB, { LOADAF(1, 1) },                  { STA(1, t + 3, 0); });
    DOPHASE(6, 1, 0, bA, {},                                { STB(1, t + 3, 0); });
  }
  {
    const int t = nt - 2;  // tail: stages only t+1's remaining halves
    DOPHASE(6, 0, 0, bA, { LOADAF(0, 0) LOADBF(0, 0, bA) }, { STB(1, t + 1, 1); });
    DOPHASE(6, 0, 1, bB, { LOADBF(0, 1, bB) },              { STA(1, t + 1, 1); });
    DOPHASE(6, 1, 1, bB, { LOADAF(0, 1) },                  {});
    DOPHASE(6, 1, 0, bA, {},                                {});
    DOPHASE(4, 0, 0, bA, { LOADAF(1, 0) LOADBF(1, 0, bA) }, {});
    DOPHASE(2, 0, 1, bB, { LOADBF(1, 1, bB) },              {});
    DOPHASE(0, 1, 1, bB, { LOADAF(1, 1) },                  {});
    DOPHASE(0, 1, 0, bA, {},                                {});
  }

  const int r_lo = (lane >> 4) << 2;
  const int col0 = (int)blockIdx.y * 256 + wn * 64 + (lane & 15);
  const int row00 = (int)blockIdx.x * 256 + wm * 128 + r_lo;
#pragma unroll
  for (int mf = 0; mf < 8; ++mf)
#pragma unroll
    for (int nf = 0; nf < 4; ++nf)
#pragma unroll
      for (int j = 0; j < 4; ++j) {
        float v = acc[mf][nf][j];
        size_t off = (size_t)(row00 + mf * 16 + j) * ldc + col0 + nf * 16;
        if constexpr (MODE == 0) {
          v = 0.5f * v * (1.0f + erff(v * 0.70710678118654752f));
          Hout[off] = (half_t)v;
        } else {
          atomicAdd(&Cout[off], v);
        }
      }
}

extern "C" void kernel_launch(void* const* d_in, const int* in_sizes, int n_in,
                              void* d_out, int out_size, void* d_ws, size_t ws_size,
                              hipStream_t stream) {
  const float* x   = (const float*)d_in[0];
  const float* bw1 = (const float*)d_in[1];
  const float* sw1 = (const float*)d_in[2];
  const float* sc1 = (const float*)d_in[3];
  const float* bw2 = (const float*)d_in[4];
  const float* sw2 = (const float*)d_in[5];
  const float* sc2 = (const float*)d_in[6];
  float* out = (float*)d_out;

  const int LDK1 = 9216 + 64;
  const int LDK2 = 36864 + 64;
  const int LDK2H = 18432 + 64;

  half_t* Wbuf = (half_t*)d_ws;
  const size_t W_HALVES  = (size_t)4096 * LDK1;
  const size_t AF_HALVES = (size_t)4096 * LDK2;
  const size_t A2_HALVES = (size_t)4096 * LDK2H;
  const size_t A1_HALVES = (size_t)4096 * LDK1;
  const size_t HH_HALVES = (size_t)4096 * 4096;
  int abuf_chunks = 1;
  if (ws_size >= (W_HALVES + AF_HALVES + HH_HALVES) * sizeof(half_t))
    abuf_chunks = 4;
  else if (ws_size >= (W_HALVES + A2_HALVES + HH_HALVES) * sizeof(half_t))
    abuf_chunks = 2;
  half_t* Abuf = Wbuf + W_HALVES;
  half_t* Hh   = Abuf + (abuf_chunks == 4 ? AF_HALVES
                         : abuf_chunks == 2 ? A2_HALVES : A1_HALVES);

  const int T = 256;
  const int NB = (4096 * 1024) / T;

  // ---- layer 1 (expand1 also writes out = x, the residual baseline) ----
  wconv_kernel<<<NB, T, 0, stream>>>(bw1, sw1, sc1, Wbuf, 10, LDK1);
  expand_kernel<float><<<NB, T, 0, stream>>>(x, Abuf, 1024, 0, 0, LDK1, out);
  gemm8_kernel<0><<<dim3(16, 16, 1), 512, 0, stream>>>(
      Abuf, Wbuf, LDK1, LDK1, 9216, nullptr, Hh, 4096);

  // ---- layer 2: W2 rows [o][LDK2], data K-contiguous in [0,36864) ----
  wconv_kernel<<<NB, T, 0, stream>>>(bw2, sw2, sc2, Wbuf, 12, LDK2);
  if (abuf_chunks == 4) {
    expand4_kernel<<<4 * NB, T, 0, stream>>>(Hh, Abuf, LDK2);
    gemm8_kernel<4><<<dim3(16, 4, 4), 512, 0, stream>>>(
        Abuf, Wbuf, LDK2, LDK2, 9216, out, nullptr, 1024);
  } else if (abuf_chunks == 2) {
    for (int c = 0; c < 2; ++c) {
      expand_kernel<half_t><<<NB, T, 0, stream>>>(Hh, Abuf, 4096, c * 2048, 0, LDK2H, nullptr);
      expand_kernel<half_t><<<NB, T, 0, stream>>>(Hh, Abuf, 4096, c * 2048 + 1024, 1, LDK2H, nullptr);
      gemm8_kernel<4><<<dim3(16, 4, 4), 512, 0, stream>>>(
          Abuf, Wbuf + (size_t)c * 18432, LDK2H, LDK2, 4608, out, nullptr, 1024);
    }
  } else {
    for (int c = 0; c < 4; ++c) {
      expand_kernel<half_t><<<NB, T, 0, stream>>>(Hh, Abuf, 4096, c * 1024, 0, LDK1, nullptr);
      gemm8_kernel<4><<<dim3(16, 4, 4), 512, 0, stream>>>(
          Abuf, Wbuf + (size_t)c * 9216, LDK1, LDK2, 2304, out, nullptr, 1024);
    }
  }
}